// Round 3
// baseline (472.184 us; speedup 1.0000x reference)
//
#include <hip/hip_runtime.h>
#include <hip/hip_bf16.h>

#define NROWS 100000
#define NEDGE 1600000
#define CIN   256
#define COUT  128

typedef __bf16 bf16x8 __attribute__((ext_vector_type(8)));
typedef float  floatx4 __attribute__((ext_vector_type(4)));

// ---------------------------------------------------------------------------
// Kernel P: prepack W (f32) -> bf16 fragment-major wpack[4096*8]   (round-1,
// harness-proven).  entry encodes W[t*16 + (l8&15)][ks*32 + (l8>>4)*8 + j]
// ---------------------------------------------------------------------------
__global__ __launch_bounds__(256) void prepack_kernel(
    const float* __restrict__ W, __bf16* __restrict__ wpack)
{
    const int f  = blockIdx.x * 256 + threadIdx.x;   // 0..4095
    const int g  = f >> 6;
    const int l8 = f & 63;
    const int ks = g >> 3;
    const int t  = g & 7;
    const int mr = l8 & 15;
    const int kg = l8 >> 4;
    const float* wp = W + (size_t)(t * 16 + mr) * CIN + ks * 32 + kg * 8;
    floatx4 w0 = *(const floatx4*)(wp);
    floatx4 w1 = *(const floatx4*)(wp + 4);
    bf16x8 b;
#pragma unroll
    for (int j = 0; j < 4; j++) {
        b[j]     = (__bf16)w0[j];
        b[4 + j] = (__bf16)w1[j];
    }
    *(bf16x8*)(wpack + (size_t)f * 8) = b;
}

// ---------------------------------------------------------------------------
// Kernel R: per-edge rank within its row (round-1, harness-proven).
// ---------------------------------------------------------------------------
__global__ __launch_bounds__(256) void rank_kernel(
    const int* __restrict__ rows, int* __restrict__ cnt,
    unsigned char* __restrict__ kaux)
{
    const int e = blockIdx.x * 256 + threadIdx.x;
    if (e < NEDGE)
        kaux[e] = (unsigned char)atomicAdd(&cnt[rows[e]], 1);
}

// ---------------------------------------------------------------------------
// Kernel S1: per-block exclusive scan of cnt (1024/block) -> off, totals->bsum
// (round-1, harness-proven). 98 blocks cover 100352 >= NROWS.
// ---------------------------------------------------------------------------
__global__ __launch_bounds__(1024) void scan_block_kernel(
    const int* __restrict__ cnt, int* __restrict__ off, int* __restrict__ bsum)
{
    __shared__ int s[1024];
    const int t = threadIdx.x;
    const int i = blockIdx.x * 1024 + t;
    const int v = (i < NROWS) ? cnt[i] : 0;
    s[t] = v;
    __syncthreads();
#pragma unroll
    for (int d = 1; d < 1024; d <<= 1) {
        const int x = (t >= d) ? s[t - d] : 0;
        __syncthreads();
        s[t] += x;
        __syncthreads();
    }
    if (i < NROWS) off[i] = s[t] - v;          // exclusive within block
    if (t == 1023) bsum[blockIdx.x] = s[t];    // block total
}

// ---------------------------------------------------------------------------
// Kernel S2: exclusive scan of the 98 block totals (round-1, proven).
// ---------------------------------------------------------------------------
__global__ __launch_bounds__(128) void scan_top_kernel(int* __restrict__ bsum)
{
    __shared__ int s[128];
    const int t = threadIdx.x;
    const int v = (t < 98) ? bsum[t] : 0;
    s[t] = v;
    __syncthreads();
#pragma unroll
    for (int d = 1; d < 128; d <<= 1) {
        const int x = (t >= d) ? s[t - d] : 0;
        __syncthreads();
        s[t] += x;
        __syncthreads();
    }
    if (t < 98) bsum[t] = s[t] - v;
}

// ---------------------------------------------------------------------------
// Kernel S3: atomic-free scatter into CSR (round-1, proven).
// edge word: col (17b) | v15 (15b)
// ---------------------------------------------------------------------------
__global__ __launch_bounds__(256) void scatter_kernel(
    const int* __restrict__ rows, const int* __restrict__ cols,
    const float* __restrict__ vals,
    const int* __restrict__ off, const int* __restrict__ bsum,
    const unsigned char* __restrict__ kaux,
    unsigned int* __restrict__ edges)
{
    const int e = blockIdx.x * 256 + threadIdx.x;
    if (e < NEDGE) {
        const int r   = rows[e];
        const int pos = off[r] + bsum[r >> 10] + (int)kaux[e];
        const int v15 = (int)(vals[e] * 32767.0f + 0.5f);
        edges[pos] = (unsigned int)cols[e] | ((unsigned int)v15 << 17);
    }
}

// ---------------------------------------------------------------------------
// Kernel G (NEW, the only change vs round-1): feat = (emb.*mask1)@W^T + b_fc.
// 512 thr = 8 waves; block owns 128 rows; wave owns 16 rows x all 8 t-frags.
// K in 8 chunks of 32 floats: emb+mask chunk (32 KB) staged via
// global_load_lds width-16 into double-buffered 64 KB LDS -> every staging
// instruction covers contiguous 128 B row-runs (vs 16x32 B segmented loads
// before, which were latency-bound at 1.3 TB/s).
// Swizzle (rule 21, both-sides): LDS dest linear; global SOURCE block index
// c^(r&7); ds_read applies the same XOR -> conflict-free b128 reads.
//   LDS[r][c] = global[r][c ^ (r&7)]  (c = 16B block 0..7 within 32-float chunk)
//   read block (cb ^ sw), sw = mrow&7 = r&7  -> global block cb.  ✓
// Fragment conventions identical to validated rounds:
//   A-frag: A[m=lane&15][k=(lane>>4)*8+j]; C/D: col=lane&15, row=(lane>>4)*4+r
// ---------------------------------------------------------------------------
__global__ __launch_bounds__(512, 4) void gemm_kernel(
    const float* __restrict__ emb, const float* __restrict__ mask1,
    const __bf16* __restrict__ wpack, const float* __restrict__ b_fc,
    __bf16* __restrict__ feat)
{
    __shared__ float sbuf[16384];   // 64 KB: [2 buf][emb 4096 f | mask 4096 f]

    const int tid  = threadIdx.x;
    const int wave = tid >> 6;          // 0..7 : row-group
    const int lane = tid & 63;
    const int mrow = lane & 15;
    const int kgrp = lane >> 4;
    const int m0   = blockIdx.x * 128;

    floatx4 acc[8];
#pragma unroll
    for (int t = 0; t < 8; t++) acc[t] = (floatx4){0.f, 0.f, 0.f, 0.f};

    // stage one 32-float k-chunk (emb+mask for 128 rows) into buffer `buf`
    auto STAGE = [&](int buf, int chunk) {
#pragma unroll
        for (int j = 0; j < 4; j++) {
            const int L  = (wave * 4 + j) * 64 + lane;   // 0..2047
            const int Li = L & 1023;
            const int r  = Li >> 3;                      // row 0..127
            const int c  = Li & 7;                       // 16B block in chunk
            int rg = m0 + r;
            if (rg >= NROWS) rg = NROWS - 1;             // clamp; stores guarded
            const float* base = (L < 1024) ? emb : mask1;
            const float* src  = base + (size_t)rg * CIN + chunk * 32
                                     + ((c ^ (r & 7)) << 2);
            float* dst = sbuf + buf * 8192 + L * 4;      // linear dest
            __builtin_amdgcn_global_load_lds(
                (const __attribute__((address_space(1))) void*)src,
                (__attribute__((address_space(3))) void*)dst, 16, 0, 0);
        }
    };

    auto COMPUTE = [&](int buf, int ks) {
        const int r  = wave * 16 + mrow;
        const int sw = mrow & 7;                         // == r & 7
        const float* rb = sbuf + buf * 8192 + r * 32;
        const int cb0 = kgrp * 2;
        floatx4 a0 = *(const floatx4*)(rb + (((cb0    ) ^ sw) << 2));
        floatx4 a1 = *(const floatx4*)(rb + (((cb0 + 1) ^ sw) << 2));
        floatx4 p0 = *(const floatx4*)(rb + 4096 + (((cb0    ) ^ sw) << 2));
        floatx4 p1 = *(const floatx4*)(rb + 4096 + (((cb0 + 1) ^ sw) << 2));
        bf16x8 x;
#pragma unroll
        for (int j = 0; j < 4; j++) {
            x[j]     = (__bf16)(a0[j] * p0[j]);
            x[4 + j] = (__bf16)(a1[j] * p1[j]);
        }
        const __bf16* bp = wpack + (size_t)ks * 4096 + (size_t)lane * 8;
#pragma unroll
        for (int t = 0; t < 8; t++) {
            bf16x8 b = *(const bf16x8*)(bp + (size_t)t * 512);
            acc[t] = __builtin_amdgcn_mfma_f32_16x16x32_bf16(x, b, acc[t], 0, 0, 0);
        }
    };

    int buf = 0;
    STAGE(0, 0);
    __syncthreads();
#pragma unroll
    for (int ks = 0; ks < 8; ks++) {
        if (ks < 7) STAGE(buf ^ 1, ks + 1);
        COMPUTE(buf, ks);
        __syncthreads();
        buf ^= 1;
    }

#pragma unroll
    for (int t = 0; t < 8; t++) {
        const int col = t * 16 + mrow;
        const float bc = b_fc[col];
#pragma unroll
        for (int rr = 0; rr < 4; rr++) {
            const int row = m0 + wave * 16 + kgrp * 4 + rr;
            if (row < NROWS)
                feat[(size_t)row * COUT + col] = (__bf16)(acc[t][rr] + bc);
        }
    }
}

// ---------------------------------------------------------------------------
// Kernel A: CSR gather + fused epilogue (round-1, harness-proven;
// bsum chunking row>>10 to match scan1024).
// ---------------------------------------------------------------------------
__global__ __launch_bounds__(256) void gather_kernel(
    const __bf16* __restrict__ feat, const int* __restrict__ off,
    const int* __restrict__ cnt, const int* __restrict__ bsum,
    const unsigned int* __restrict__ edges,
    const float* __restrict__ bias, const float* __restrict__ mask2,
    const float* __restrict__ prelu_a, float* __restrict__ out)
{
    const int tid  = threadIdx.x;
    const int wave = tid >> 6;
    const int lane = tid & 63;
    const int q    = lane >> 4;
    const int l16  = lane & 15;
    const int row  = blockIdx.x * 16 + wave * 4 + q;   // grid exact: 6250*16
    const int c8   = l16 * 8;

    const int beg = off[row] + bsum[row >> 10];
    const int end = beg + cnt[row];

    float acc[8];
#pragma unroll
    for (int j = 0; j < 8; j++) acc[j] = 0.f;

    int e = beg;
    for (; e + 4 <= end; e += 4) {
        const unsigned int u0 = edges[e + 0];
        const unsigned int u1 = edges[e + 1];
        const unsigned int u2 = edges[e + 2];
        const unsigned int u3 = edges[e + 3];
        const bf16x8 h0 = *(const bf16x8*)(feat + (size_t)(u0 & 0x1FFFFu) * COUT + c8);
        const bf16x8 h1 = *(const bf16x8*)(feat + (size_t)(u1 & 0x1FFFFu) * COUT + c8);
        const bf16x8 h2 = *(const bf16x8*)(feat + (size_t)(u2 & 0x1FFFFu) * COUT + c8);
        const bf16x8 h3 = *(const bf16x8*)(feat + (size_t)(u3 & 0x1FFFFu) * COUT + c8);
        const float v0 = (float)(u0 >> 17) * (1.0f / 32767.0f);
        const float v1 = (float)(u1 >> 17) * (1.0f / 32767.0f);
        const float v2 = (float)(u2 >> 17) * (1.0f / 32767.0f);
        const float v3 = (float)(u3 >> 17) * (1.0f / 32767.0f);
#pragma unroll
        for (int j = 0; j < 8; j++)
            acc[j] += v0 * (float)h0[j] + v1 * (float)h1[j]
                    + v2 * (float)h2[j] + v3 * (float)h3[j];
    }
    for (; e < end; ++e) {
        const unsigned int u = edges[e];
        const bf16x8 h = *(const bf16x8*)(feat + (size_t)(u & 0x1FFFFu) * COUT + c8);
        const float v = (float)(u >> 17) * (1.0f / 32767.0f);
#pragma unroll
        for (int j = 0; j < 8; j++) acc[j] += v * (float)h[j];
    }

    const float pa = prelu_a[0];
    const floatx4 b0 = *(const floatx4*)(bias + c8);
    const floatx4 b1 = *(const floatx4*)(bias + c8 + 4);
    const floatx4 m0 = *(const floatx4*)(mask2 + (size_t)row * COUT + c8);
    const floatx4 m1 = *(const floatx4*)(mask2 + (size_t)row * COUT + c8 + 4);
    floatx4 o0, o1;
#pragma unroll
    for (int j = 0; j < 4; j++) {
        const float t0 = (acc[j]     + b0[j]) * m0[j];
        const float t1 = (acc[4 + j] + b1[j]) * m1[j];
        o0[j] = (t0 > 0.f) ? t0 : pa * t0;
        o1[j] = (t1 > 0.f) ? t1 : pa * t1;
    }
    *(floatx4*)(out + (size_t)row * COUT + c8)     = o0;
    *(floatx4*)(out + (size_t)row * COUT + c8 + 4) = o1;
}

// ---------------------------------------------------------------------------
extern "C" void kernel_launch(void* const* d_in, const int* in_sizes, int n_in,
                              void* d_out, int out_size, void* d_ws, size_t ws_size,
                              hipStream_t stream)
{
    const float* emb     = (const float*)d_in[0];
    const float* vals    = (const float*)d_in[1];
    const float* W       = (const float*)d_in[2];
    const float* b_fc    = (const float*)d_in[3];
    const float* bias    = (const float*)d_in[4];
    const float* prelu_a = (const float*)d_in[5];
    const float* mask1   = (const float*)d_in[6];
    const float* mask2   = (const float*)d_in[7];
    const int*   rows    = (const int*)d_in[8];
    const int*   cols    = (const int*)d_in[9];

    char* ws = (char*)d_ws;
    // ws layout (disjoint, 16B-aligned), total 34,466,048 B
    __bf16*        feat  = (__bf16*)(ws);                        // 25,600,000
    int*           cnt   = (int*)(ws + 25600000);                //    400,000
    int*           off   = (int*)(ws + 26000000);                //    400,000
    unsigned int*  edges = (unsigned int*)(ws + 26400000);       //  6,400,000
    int*           bsum  = (int*)(ws + 32800000);                //        512
    unsigned char* kaux  = (unsigned char*)(ws + 32800512);      //  1,600,000
    __bf16*        wpack = (__bf16*)(ws + 34400512);             //     65,536

    hipMemsetAsync(cnt, 0, 400000, stream);

    prepack_kernel<<<16, 256, 0, stream>>>(W, wpack);
    rank_kernel<<<NEDGE / 256, 256, 0, stream>>>(rows, cnt, kaux);
    scan_block_kernel<<<98, 1024, 0, stream>>>(cnt, off, bsum);
    scan_top_kernel<<<1, 128, 0, stream>>>(bsum);
    scatter_kernel<<<NEDGE / 256, 256, 0, stream>>>(rows, cols, vals,
                                                    off, bsum, kaux, edges);
    gemm_kernel<<<(NROWS + 127) / 128, 512, 0, stream>>>(emb, mask1, wpack,
                                                         b_fc, feat);
    gather_kernel<<<NROWS / 16, 256, 0, stream>>>(feat, off, cnt, bsum, edges,
                                                  bias, mask2, prelu_a,
                                                  (float*)d_out);
}

// Round 4
// 451.045 us; speedup vs baseline: 1.0469x; 1.0469x over previous
//
#include <hip/hip_runtime.h>
#include <hip/hip_bf16.h>

#define NROWS 100000
#define NEDGE 1600000
#define CIN   256
#define COUT  128
#define GEMM_BLOCKS 1563   // ceil(NROWS/64): 4 waves x 16 rows per block
#define RANK_BLOCKS 6250   // NEDGE/256

typedef __bf16 bf16x8 __attribute__((ext_vector_type(8)));
typedef float  floatx4 __attribute__((ext_vector_type(4)));

// ---------------------------------------------------------------------------
// Kernel P: prepack W (f32) -> bf16 fragment-major wpack[4096*8]  (proven).
// entry encodes W[t*16 + (l8&15)][ks*32 + (l8>>4)*8 + j]
// ---------------------------------------------------------------------------
__global__ __launch_bounds__(256) void prepack_kernel(
    const float* __restrict__ W, __bf16* __restrict__ wpack)
{
    const int f  = blockIdx.x * 256 + threadIdx.x;   // 0..4095
    const int g  = f >> 6;
    const int l8 = f & 63;
    const int ks = g >> 3;
    const int t  = g & 7;
    const int mr = l8 & 15;
    const int kg = l8 >> 4;
    const float* wp = W + (size_t)(t * 16 + mr) * CIN + ks * 32 + kg * 8;
    floatx4 w0 = *(const floatx4*)(wp);
    floatx4 w1 = *(const floatx4*)(wp + 4);
    bf16x8 b;
#pragma unroll
    for (int j = 0; j < 4; j++) {
        b[j]     = (__bf16)w0[j];
        b[4 + j] = (__bf16)w1[j];
    }
    *(bf16x8*)(wpack + (size_t)f * 8) = b;
}

// ---------------------------------------------------------------------------
// FAT kernel: co-schedules two INDEPENDENT proven bodies to overlap the
// atomic-latency-bound rank phase with the bandwidth-starved gemm phase.
//   blocks [0, GEMM_BLOCKS)                : gemm body (64 rows/block)
//   blocks [GEMM_BLOCKS, +RANK_BLOCKS)     : rank body (256 edges/block)
// gemm body = round-1 register version (harness-proven math) with prefetch
// depth extended 1 -> 2 (named-register rotation in fully-unrolled loop).
// ---------------------------------------------------------------------------
__global__ __launch_bounds__(256) void fat_kernel(
    const float* __restrict__ emb, const float* __restrict__ mask1,
    const __bf16* __restrict__ wpack, const float* __restrict__ b_fc,
    __bf16* __restrict__ feat,
    const int* __restrict__ rows, int* __restrict__ cnt,
    unsigned char* __restrict__ kaux)
{
    if (blockIdx.x >= GEMM_BLOCKS) {
        // ---------------- rank body (proven) ----------------
        const int e = (blockIdx.x - GEMM_BLOCKS) * 256 + threadIdx.x;
        if (e < NEDGE)
            kaux[e] = (unsigned char)atomicAdd(&cnt[rows[e]], 1);
        return;
    }

    // ---------------- gemm body ----------------
    const int tid  = threadIdx.x;
    const int wave = tid >> 6;
    const int lane = tid & 63;
    const int mrow = lane & 15;
    const int kgrp = lane >> 4;
    const int m0   = blockIdx.x * 64 + wave * 16;

    int mA = m0 + mrow;
    if (mA >= NROWS) mA = NROWS - 1;            // clamp loads; stores guarded
    const float* ea = emb   + (size_t)mA * CIN;
    const float* qa = mask1 + (size_t)mA * CIN;
    const int kofs = kgrp * 8;

    floatx4 acc[8];
#pragma unroll
    for (int t = 0; t < 8; t++) acc[t] = (floatx4){0.f, 0.f, 0.f, 0.f};

    // depth-2 prefetch pipeline: chunks ks, ks+1 resident; ks+2 in flight
    floatx4 a0_0 = *(const floatx4*)(ea + kofs);
    floatx4 a1_0 = *(const floatx4*)(ea + kofs + 4);
    floatx4 p0_0 = *(const floatx4*)(qa + kofs);
    floatx4 p1_0 = *(const floatx4*)(qa + kofs + 4);
    floatx4 a0_1 = *(const floatx4*)(ea + 32 + kofs);
    floatx4 a1_1 = *(const floatx4*)(ea + 32 + kofs + 4);
    floatx4 p0_1 = *(const floatx4*)(qa + 32 + kofs);
    floatx4 p1_1 = *(const floatx4*)(qa + 32 + kofs + 4);

#pragma unroll
    for (int ks = 0; ks < 8; ks++) {
        floatx4 a0_2, a1_2, p0_2, p1_2;
        if (ks < 6) {
            const int k0 = (ks + 2) * 32 + kofs;
            a0_2 = *(const floatx4*)(ea + k0);
            a1_2 = *(const floatx4*)(ea + k0 + 4);
            p0_2 = *(const floatx4*)(qa + k0);
            p1_2 = *(const floatx4*)(qa + k0 + 4);
        }
        bf16x8 x;
#pragma unroll
        for (int j = 0; j < 4; j++) {
            x[j]     = (__bf16)(a0_0[j] * p0_0[j]);
            x[4 + j] = (__bf16)(a1_0[j] * p1_0[j]);
        }
        const __bf16* bp = wpack + (size_t)ks * 4096 + (size_t)lane * 8;
#pragma unroll
        for (int t = 0; t < 8; t++) {
            bf16x8 b = *(const bf16x8*)(bp + (size_t)t * 512);
            acc[t] = __builtin_amdgcn_mfma_f32_16x16x32_bf16(x, b, acc[t], 0, 0, 0);
        }
        // rotate pipeline (register renames after full unroll)
        a0_0 = a0_1; a1_0 = a1_1; p0_0 = p0_1; p1_0 = p1_1;
        if (ks < 6) { a0_1 = a0_2; a1_1 = a1_2; p0_1 = p0_2; p1_1 = p1_2; }
    }

#pragma unroll
    for (int t = 0; t < 8; t++) {
        const int col = t * 16 + mrow;
        const float bc = b_fc[col];
#pragma unroll
        for (int r = 0; r < 4; r++) {
            const int row = m0 + kgrp * 4 + r;
            if (row < NROWS)
                feat[(size_t)row * COUT + col] = (__bf16)(acc[t][r] + bc);
        }
    }
}

// ---------------------------------------------------------------------------
// Kernel S1: per-block exclusive scan of cnt (1024/block) -> off, totals->bsum
// (proven). 98 blocks cover 100352 >= NROWS.
// ---------------------------------------------------------------------------
__global__ __launch_bounds__(1024) void scan_block_kernel(
    const int* __restrict__ cnt, int* __restrict__ off, int* __restrict__ bsum)
{
    __shared__ int s[1024];
    const int t = threadIdx.x;
    const int i = blockIdx.x * 1024 + t;
    const int v = (i < NROWS) ? cnt[i] : 0;
    s[t] = v;
    __syncthreads();
#pragma unroll
    for (int d = 1; d < 1024; d <<= 1) {
        const int x = (t >= d) ? s[t - d] : 0;
        __syncthreads();
        s[t] += x;
        __syncthreads();
    }
    if (i < NROWS) off[i] = s[t] - v;          // exclusive within block
    if (t == 1023) bsum[blockIdx.x] = s[t];    // block total
}

// ---------------------------------------------------------------------------
// Kernel S2: exclusive scan of the 98 block totals (proven).
// ---------------------------------------------------------------------------
__global__ __launch_bounds__(128) void scan_top_kernel(int* __restrict__ bsum)
{
    __shared__ int s[128];
    const int t = threadIdx.x;
    const int v = (t < 98) ? bsum[t] : 0;
    s[t] = v;
    __syncthreads();
#pragma unroll
    for (int d = 1; d < 128; d <<= 1) {
        const int x = (t >= d) ? s[t - d] : 0;
        __syncthreads();
        s[t] += x;
        __syncthreads();
    }
    if (t < 98) bsum[t] = s[t] - v;
}

// ---------------------------------------------------------------------------
// Kernel S3: atomic-free scatter into CSR (proven).
// edge word: col (17b) | v15 (15b)
// ---------------------------------------------------------------------------
__global__ __launch_bounds__(256) void scatter_kernel(
    const int* __restrict__ rows, const int* __restrict__ cols,
    const float* __restrict__ vals,
    const int* __restrict__ off, const int* __restrict__ bsum,
    const unsigned char* __restrict__ kaux,
    unsigned int* __restrict__ edges)
{
    const int e = blockIdx.x * 256 + threadIdx.x;
    if (e < NEDGE) {
        const int r   = rows[e];
        const int pos = off[r] + bsum[r >> 10] + (int)kaux[e];
        const int v15 = (int)(vals[e] * 32767.0f + 0.5f);
        edges[pos] = (unsigned int)cols[e] | ((unsigned int)v15 << 17);
    }
}

// ---------------------------------------------------------------------------
// Kernel A: CSR gather + fused epilogue (proven; bsum chunk row>>10).
// ---------------------------------------------------------------------------
__global__ __launch_bounds__(256) void gather_kernel(
    const __bf16* __restrict__ feat, const int* __restrict__ off,
    const int* __restrict__ cnt, const int* __restrict__ bsum,
    const unsigned int* __restrict__ edges,
    const float* __restrict__ bias, const float* __restrict__ mask2,
    const float* __restrict__ prelu_a, float* __restrict__ out)
{
    const int tid  = threadIdx.x;
    const int wave = tid >> 6;
    const int lane = tid & 63;
    const int q    = lane >> 4;
    const int l16  = lane & 15;
    const int row  = blockIdx.x * 16 + wave * 4 + q;   // grid exact: 6250*16
    const int c8   = l16 * 8;

    const int beg = off[row] + bsum[row >> 10];
    const int end = beg + cnt[row];

    float acc[8];
#pragma unroll
    for (int j = 0; j < 8; j++) acc[j] = 0.f;

    int e = beg;
    for (; e + 4 <= end; e += 4) {
        const unsigned int u0 = edges[e + 0];
        const unsigned int u1 = edges[e + 1];
        const unsigned int u2 = edges[e + 2];
        const unsigned int u3 = edges[e + 3];
        const bf16x8 h0 = *(const bf16x8*)(feat + (size_t)(u0 & 0x1FFFFu) * COUT + c8);
        const bf16x8 h1 = *(const bf16x8*)(feat + (size_t)(u1 & 0x1FFFFu) * COUT + c8);
        const bf16x8 h2 = *(const bf16x8*)(feat + (size_t)(u2 & 0x1FFFFu) * COUT + c8);
        const bf16x8 h3 = *(const bf16x8*)(feat + (size_t)(u3 & 0x1FFFFu) * COUT + c8);
        const float v0 = (float)(u0 >> 17) * (1.0f / 32767.0f);
        const float v1 = (float)(u1 >> 17) * (1.0f / 32767.0f);
        const float v2 = (float)(u2 >> 17) * (1.0f / 32767.0f);
        const float v3 = (float)(u3 >> 17) * (1.0f / 32767.0f);
#pragma unroll
        for (int j = 0; j < 8; j++)
            acc[j] += v0 * (float)h0[j] + v1 * (float)h1[j]
                    + v2 * (float)h2[j] + v3 * (float)h3[j];
    }
    for (; e < end; ++e) {
        const unsigned int u = edges[e];
        const bf16x8 h = *(const bf16x8*)(feat + (size_t)(u & 0x1FFFFu) * COUT + c8);
        const float v = (float)(u >> 17) * (1.0f / 32767.0f);
#pragma unroll
        for (int j = 0; j < 8; j++) acc[j] += v * (float)h[j];
    }

    const float pa = prelu_a[0];
    const floatx4 b0 = *(const floatx4*)(bias + c8);
    const floatx4 b1 = *(const floatx4*)(bias + c8 + 4);
    const floatx4 m0 = *(const floatx4*)(mask2 + (size_t)row * COUT + c8);
    const floatx4 m1 = *(const floatx4*)(mask2 + (size_t)row * COUT + c8 + 4);
    floatx4 o0, o1;
#pragma unroll
    for (int j = 0; j < 4; j++) {
        const float t0 = (acc[j]     + b0[j]) * m0[j];
        const float t1 = (acc[4 + j] + b1[j]) * m1[j];
        o0[j] = (t0 > 0.f) ? t0 : pa * t0;
        o1[j] = (t1 > 0.f) ? t1 : pa * t1;
    }
    *(floatx4*)(out + (size_t)row * COUT + c8)     = o0;
    *(floatx4*)(out + (size_t)row * COUT + c8 + 4) = o1;
}

// ---------------------------------------------------------------------------
extern "C" void kernel_launch(void* const* d_in, const int* in_sizes, int n_in,
                              void* d_out, int out_size, void* d_ws, size_t ws_size,
                              hipStream_t stream)
{
    const float* emb     = (const float*)d_in[0];
    const float* vals    = (const float*)d_in[1];
    const float* W       = (const float*)d_in[2];
    const float* b_fc    = (const float*)d_in[3];
    const float* bias    = (const float*)d_in[4];
    const float* prelu_a = (const float*)d_in[5];
    const float* mask1   = (const float*)d_in[6];
    const float* mask2   = (const float*)d_in[7];
    const int*   rows    = (const int*)d_in[8];
    const int*   cols    = (const int*)d_in[9];

    char* ws = (char*)d_ws;
    // ws layout (disjoint, 16B-aligned), total 34,466,048 B
    __bf16*        feat  = (__bf16*)(ws);                        // 25,600,000
    int*           cnt   = (int*)(ws + 25600000);                //    400,000
    int*           off   = (int*)(ws + 26000000);                //    400,000
    unsigned int*  edges = (unsigned int*)(ws + 26400000);       //  6,400,000
    int*           bsum  = (int*)(ws + 32800000);                //        512
    unsigned char* kaux  = (unsigned char*)(ws + 32800512);      //  1,600,000
    __bf16*        wpack = (__bf16*)(ws + 34400512);             //     65,536

    hipMemsetAsync(cnt, 0, 400000, stream);

    prepack_kernel<<<16, 256, 0, stream>>>(W, wpack);
    fat_kernel<<<GEMM_BLOCKS + RANK_BLOCKS, 256, 0, stream>>>(
        emb, mask1, wpack, b_fc, feat, rows, cnt, kaux);
    scan_block_kernel<<<98, 1024, 0, stream>>>(cnt, off, bsum);
    scan_top_kernel<<<1, 128, 0, stream>>>(bsum);
    scatter_kernel<<<NEDGE / 256, 256, 0, stream>>>(rows, cols, vals,
                                                    off, bsum, kaux, edges);
    gather_kernel<<<NROWS / 16, 256, 0, stream>>>(feat, off, cnt, bsum, edges,
                                                  bias, mask2, prelu_a,
                                                  (float*)d_out);
}